// Round 4
// baseline (796.680 us; speedup 1.0000x reference)
//
#include <hip/hip_runtime.h>
#include <math.h>

typedef __bf16 bf16_t;
typedef __bf16 bf16x8 __attribute__((ext_vector_type(8)));
typedef __bf16 bf16x4 __attribute__((ext_vector_type(4)));
typedef float  f32x4  __attribute__((ext_vector_type(4)));

#define DEV __device__ __forceinline__

// q pre-scale: 1/sqrt(64) * log2(e), folded into q GEMM epilogue
#define QSCALE 0.18033688011112042f
// 1e10 * log2(e) for the mask penalty (in exp2 domain)
#define MASKF  1.4426950408889634e10f

DEV float fexp2(float x) {
#if __has_builtin(__builtin_amdgcn_exp2f)
  return __builtin_amdgcn_exp2f(x);
#else
  return __expf(x * 0.6931471805599453f);
#endif
}

DEV void gl_lds16(const bf16_t* g, bf16_t* l) {
  __builtin_amdgcn_global_load_lds(
      (const __attribute__((address_space(1))) void*)g,
      (__attribute__((address_space(3))) void*)l, 16, 0, 0);
}

// ---------------- cast f32 -> bf16 (vectorized) ----------------
__global__ void k_cast_bf16(const float* __restrict__ src, bf16_t* __restrict__ dst, int n4) {
  int idx = blockIdx.x * blockDim.x + threadIdx.x;
  int stride = gridDim.x * blockDim.x;
  const float4* s4 = (const float4*)src;
  for (int i = idx; i < n4; i += stride) {
    float4 v = s4[i];
    bf16x4 o;
    o[0] = (bf16_t)v.x; o[1] = (bf16_t)v.y; o[2] = (bf16_t)v.z; o[3] = (bf16_t)v.w;
    *(bf16x4*)(dst + (size_t)i * 4) = o;
  }
}

// ---------------- transpose + cast weight [1024][1024] f32 -> [N][K] bf16 ----------------
__global__ __launch_bounds__(256) void k_transpose_cast(const float* __restrict__ W, bf16_t* __restrict__ Wt) {
  __shared__ float tile[64][65];
  int k0 = blockIdx.x * 64, n0 = blockIdx.y * 64;
  int r = threadIdx.x >> 2;
  int c0 = (threadIdx.x & 3) * 16;
  const float4* src = (const float4*)(W + (size_t)(k0 + r) * 1024 + n0 + c0);
#pragma unroll
  for (int i = 0; i < 4; ++i) {
    float4 v = src[i];
    tile[r][c0 + i * 4 + 0] = v.x;
    tile[r][c0 + i * 4 + 1] = v.y;
    tile[r][c0 + i * 4 + 2] = v.z;
    tile[r][c0 + i * 4 + 3] = v.w;
  }
  __syncthreads();
#pragma unroll
  for (int half = 0; half < 2; ++half) {
    bf16x8 o;
#pragma unroll
    for (int j = 0; j < 8; ++j) o[j] = (bf16_t)tile[c0 + half * 8 + j][r];
    *(bf16x8*)(Wt + (size_t)(n0 + r) * 1024 + k0 + c0 + half * 8) = o;
  }
}

// ---------------- reversed sinusoidal table [2048][1024] bf16 ----------------
__global__ void k_sinusoid(bf16_t* __restrict__ tab) {
  int i = blockIdx.x;   // row
  int d = threadIdx.x;  // 0..511
  float pos = (float)(2047 - i);
  const float coef = (float)(-9.210340371976184 / 511.0);  // -ln(10000)/(n-1)
  float inv = expf((float)d * coef);
  float st = pos * inv;
  tab[(size_t)i * 1024 + d]       = (bf16_t)sinf(st);
  tab[(size_t)i * 1024 + 512 + d] = (bf16_t)cosf(st);
}

// ---------------- GEMM: C[M][1024] = A[M][1024] @ Bt^T, epilogue (acc+bias+eb)*scale ---------
__global__ __launch_bounds__(256) void k_gemm(
    const bf16_t* __restrict__ A, const bf16_t* __restrict__ Bt,
    const float* __restrict__ bias, const float* __restrict__ ebias, float scale,
    bf16_t* __restrict__ outB, float* __restrict__ outF) {
  __shared__ bf16_t As[128 * 64];
  __shared__ bf16_t Bs[128 * 64];
  const int m0 = blockIdx.x * 128, n0 = blockIdx.y * 128;
  const int tid = threadIdx.x;
  const int w = tid >> 6, lane = tid & 63, li = lane & 15, g = lane >> 4;
  const int mb = (w >> 1) * 64, nb = (w & 1) * 64;
  f32x4 acc[4][4] = {};
  for (int kt = 0; kt < 16; ++kt) {
    __syncthreads();
#pragma unroll
    for (int it = 0; it < 4; ++it) {
      int chunk = it * 256 + tid;
      int r = chunk >> 3, kg = chunk & 7;
      gl_lds16(A + (size_t)(m0 + r) * 1024 + kt * 64 + kg * 8, &As[chunk * 8]);
      gl_lds16(Bt + (size_t)(n0 + r) * 1024 + kt * 64 + kg * 8, &Bs[chunk * 8]);
    }
    __syncthreads();
#pragma unroll
    for (int kk = 0; kk < 64; kk += 32) {
      bf16x8 a[4], b[4];
#pragma unroll
      for (int x = 0; x < 4; ++x) {
        a[x] = *(const bf16x8*)&As[(mb + x * 16 + li) * 64 + kk + g * 8];
        b[x] = *(const bf16x8*)&Bs[(nb + x * 16 + li) * 64 + kk + g * 8];
      }
#pragma unroll
      for (int mr = 0; mr < 4; ++mr)
#pragma unroll
        for (int nr = 0; nr < 4; ++nr)
          acc[mr][nr] = __builtin_amdgcn_mfma_f32_16x16x32_bf16(a[mr], b[nr], acc[mr][nr], 0, 0, 0);
    }
  }
#pragma unroll
  for (int mr = 0; mr < 4; ++mr)
#pragma unroll
    for (int nr = 0; nr < 4; ++nr)
#pragma unroll
      for (int r4 = 0; r4 < 4; ++r4) {
        int row = m0 + mb + mr * 16 + g * 4 + r4;
        int col = n0 + nb + nr * 16 + li;
        float v = acc[mr][nr][r4] + bias[col];
        if (ebias) v += ebias[col];
        v *= scale;
        size_t off = (size_t)row * 1024 + col;
        if (outB) outB[off] = (bf16_t)v;
        if (outF) outF[off] = v;
      }
}

// ---------------- fused rel-attention ----------------
// grid 1024 linear (XCD-swizzled, head-fastest decode), 256 threads (4 waves).
// All global loads (pe fragments, mask tile) issued at top of the iter body so
// MFMA/LDS work covers their latency; K/V reg-prefetch issued mid-iter for the
// next tile. Math identical to round-3 passing version.
__global__ __launch_bounds__(256, 3) void k_attn(
    const bf16_t* __restrict__ qw, const bf16_t* __restrict__ kb,
    const bf16_t* __restrict__ vb, const bf16_t* __restrict__ peb,
    const float* __restrict__ rwb, const float* __restrict__ rrb,
    const float* __restrict__ mask, bf16_t* __restrict__ attnb) {
  // XCD-bijective swizzle: 1024 blocks, 8 XCDs, 128 per XCD chunk.
  // Decode head-fastest so one XCD's chunk shares mask rows + peb in its L2.
  const int lin  = blockIdx.x + (blockIdx.y << 5) + (blockIdx.z << 9);
  const int logi = ((lin & 7) << 7) + (lin >> 3);
  const int h  = logi & 15;
  const int t0 = ((logi >> 4) & 31) << 6;
  const int b  = logi >> 9;
  const int tid = threadIdx.x;
  const int w = tid >> 6, lane = tid & 63, li = lane & 15, g = lane >> 4;

  __shared__ __align__(16) bf16_t k_s[64 * 72];
  __shared__ __align__(16) bf16_t vt_s[64 * 72];
  __shared__ __align__(16) float R_all[4][16 * 80];
  __shared__ __align__(16) bf16_t p_all[4][16 * 72];

  float* R_w = &R_all[w][0];
  bf16_t* p_w = &p_all[w][0];

  const size_t base_bh = (size_t)b * 2048 * 1024 + (size_t)h * 64;

  // ---- prefetch K/V tile 0 into registers ----
  bf16x8 kpf[2], vpf[2];
#pragma unroll
  for (int it = 0; it < 2; ++it) {
    int c = it * 256 + tid;
    int r = c >> 3, s = c & 7;
    kpf[it] = *(const bf16x8*)(kb + base_bh + (size_t)r * 1024 + s * 8);
    vpf[it] = *(const bf16x8*)(vb + base_bh + (size_t)r * 1024 + s * 8);
  }

  // ---- hoist Q fragments (content + relA + relB) ----
  bf16x8 aq[2], arA[2], arB[2];
  {
    int rowA = t0 + w * 16 + li;
    int rowB = rowA + 1 < 2048 ? rowA + 1 : 2047;
#pragma unroll
    for (int kkh = 0; kkh < 2; ++kkh) {
      int cof = kkh * 32 + g * 8;
      aq[kkh] = *(const bf16x8*)(qw + base_bh + (size_t)rowA * 1024 + cof);
      bf16x8 qb = *(const bf16x8*)(qw + base_bh + (size_t)rowB * 1024 + cof);
#pragma unroll
      for (int j = 0; j < 8; ++j) {
        float dj = (rrb[h * 64 + cof + j] - rwb[h * 64 + cof + j]) * QSCALE;
        arA[kkh][j] = (bf16_t)((float)aq[kkh][j] + dj);
        arB[kkh][j] = (bf16_t)((float)qb[j] + dj);
      }
    }
  }

  float mrun[4], lrun[4];
  f32x4 oacc[4] = {};
#pragma unroll
  for (int r4 = 0; r4 < 4; ++r4) { mrun[r4] = -1e30f; lrun[r4] = 0.f; }

  for (int jt = 0; jt < 32; ++jt) {
    const int j0 = jt * 64;
    __syncthreads();  // BAR1: everyone done reading k_s/vt_s of prev iter
    // ---- stage K (b128) and V^T (swizzled scalar) from prefetch regs ----
#pragma unroll
    for (int it = 0; it < 2; ++it) {
      int c = it * 256 + tid;
      int r = c >> 3, s = c & 7;
      *(bf16x8*)&k_s[r * 72 + s * 8] = kpf[it];
      int up = ((r >> 3) ^ s);  // unit-XOR swizzle: conflict-free PV reads
#pragma unroll
      for (int dd = 0; dd < 8; ++dd)
        vt_s[(s * 8 + dd) * 72 + up * 8 + (r & 7)] = vpf[it][dd];
    }
    __syncthreads();  // BAR2: tile visible

    // ======== issue this iter's global loads EARLY (latency cover) ========
    // mask tile (consumed at softmax, ~700cy later)
    float mpf[4][4];
#pragma unroll
    for (int ct = 0; ct < 4; ++ct)
#pragma unroll
      for (int r4 = 0; r4 < 4; ++r4)
        mpf[ct][r4] = mask[((size_t)b * 2048 + t0 + w * 16 + g * 4 + r4) * 2048 + j0 + ct * 16 + li];
    // pe fragments for the primary rel case (consumed after content MFMAs)
    const bool topA = (j0 <= t0);
    const int c0t = topA ? (1984 + j0 - t0) : (j0 - t0 - 65);
    bf16x8 bp[5][2];
#pragma unroll
    for (int f = 0; f < 5; ++f) {
      int c = c0t + (3 - w + f) * 16 + li;
      c = c < 0 ? 0 : (c > 2047 ? 2047 : c);
#pragma unroll
      for (int kkh = 0; kkh < 2; ++kkh)
        bp[f][kkh] = *(const bf16x8*)(peb + (size_t)c * 1024 + h * 64 + kkh * 32 + g * 8);
    }

    // ---- content scores ----
    __builtin_amdgcn_s_setprio(1);
    f32x4 sc[4] = {};
#pragma unroll
    for (int kkh = 0; kkh < 2; ++kkh)
#pragma unroll
      for (int ct = 0; ct < 4; ++ct) {
        bf16x8 bk = *(const bf16x8*)&k_s[(ct * 16 + li) * 72 + kkh * 32 + g * 8];
        sc[ct] = __builtin_amdgcn_mfma_f32_16x16x32_bf16(aq[kkh], bk, sc[ct], 0, 0, 0);
      }

    // ---- relative scores: two Toeplitz cases, per-wave private R band ----
    const int sdc = j0 - t0 - w * 16;
#pragma unroll
    for (int cs = 0; cs < 2; ++cs) {
      if (cs == 0 ? (j0 > t0) : (j0 < t0)) continue;
      const int c0 = cs == 0 ? (1984 + j0 - t0) : (j0 - t0 - 65);
      const bool usePF = ((cs == 0) == topA);
      f32x4 ra[5] = {};
#pragma unroll
      for (int kkh = 0; kkh < 2; ++kkh) {
        bf16x8 a = cs ? arB[kkh] : arA[kkh];
#pragma unroll
        for (int f = 0; f < 5; ++f) {
          bf16x8 bpv;
          if (usePF) {
            bpv = bp[f][kkh];
          } else {
            int c = c0 + (3 - w + f) * 16 + li;
            c = c < 0 ? 0 : (c > 2047 ? 2047 : c);
            bpv = *(const bf16x8*)(peb + (size_t)c * 1024 + h * 64 + kkh * 32 + g * 8);
          }
          ra[f] = __builtin_amdgcn_mfma_f32_16x16x32_bf16(a, bpv, ra[f], 0, 0, 0);
        }
      }
      __builtin_amdgcn_s_setprio(0);
#pragma unroll
      for (int f = 0; f < 5; ++f)
#pragma unroll
        for (int r4 = 0; r4 < 4; ++r4)
          R_w[(g * 4 + r4) * 80 + f * 16 + li] = ra[f][r4];
      // wave-private: same-type LDS write->read, compiler orders via lgkmcnt
#pragma unroll
      for (int ct = 0; ct < 4; ++ct)
#pragma unroll
        for (int r4 = 0; r4 < 4; ++r4) {
          int il = g * 4 + r4;
          int col = ct * 16 + li - il + 15;
          float rv = R_w[il * 80 + col];
          int sd = sdc + ct * 16 + li - il;
          bool pr = cs ? (sd >= 2) : (sd <= 0);
          sc[ct][r4] += pr ? rv : 0.f;
        }
      __builtin_amdgcn_s_setprio(1);
    }
    __builtin_amdgcn_s_setprio(0);

    // ---- prefetch next K/V tile (regs free now; softmax+PV+stage covers) ----
    if (jt < 31) {
#pragma unroll
      for (int it = 0; it < 2; ++it) {
        int c = it * 256 + tid;
        int r = c >> 3, s = c & 7;
        kpf[it] = *(const bf16x8*)(kb + base_bh + (size_t)(j0 + 64 + r) * 1024 + s * 8);
        vpf[it] = *(const bf16x8*)(vb + base_bh + (size_t)(j0 + 64 + r) * 1024 + s * 8);
      }
    }

    // ---- mask + online softmax (exp2 domain) ----
    float rmax[4] = {-3e38f, -3e38f, -3e38f, -3e38f};
#pragma unroll
    for (int ct = 0; ct < 4; ++ct)
#pragma unroll
      for (int r4 = 0; r4 < 4; ++r4) {
        float s = fmaf(mpf[ct][r4] - 1.f, MASKF, sc[ct][r4]);
        sc[ct][r4] = s;
        rmax[r4] = fmaxf(rmax[r4], s);
      }
#pragma unroll
    for (int r4 = 0; r4 < 4; ++r4)
#pragma unroll
      for (int off = 1; off < 16; off <<= 1)
        rmax[r4] = fmaxf(rmax[r4], __shfl_xor(rmax[r4], off));
    float scl[4], rsum[4];
#pragma unroll
    for (int r4 = 0; r4 < 4; ++r4) {
      float mnew = fmaxf(mrun[r4], rmax[r4]);
      scl[r4] = fexp2(mrun[r4] - mnew);
      mrun[r4] = mnew;
      rsum[r4] = 0.f;
    }
#pragma unroll
    for (int ct = 0; ct < 4; ++ct)
#pragma unroll
      for (int r4 = 0; r4 < 4; ++r4) {
        float p = fexp2(sc[ct][r4] - mrun[r4]);
        sc[ct][r4] = p;
        rsum[r4] += p;
      }
#pragma unroll
    for (int r4 = 0; r4 < 4; ++r4) {
#pragma unroll
      for (int off = 1; off < 16; off <<= 1)
        rsum[r4] += __shfl_xor(rsum[r4], off);
      lrun[r4] = lrun[r4] * scl[r4] + rsum[r4];
    }
#pragma unroll
    for (int ct = 0; ct < 4; ++ct)
#pragma unroll
      for (int r4 = 0; r4 < 4; ++r4) oacc[ct][r4] *= scl[r4];

    // ---- P -> LDS (wave-private buffer) ----
#pragma unroll
    for (int ct = 0; ct < 4; ++ct)
#pragma unroll
      for (int r4 = 0; r4 < 4; ++r4)
        p_w[(g * 4 + r4) * 72 + ct * 16 + li] = (bf16_t)sc[ct][r4];

    // ---- PV ----
    __builtin_amdgcn_s_setprio(1);
#pragma unroll
    for (int kkh = 0; kkh < 2; ++kkh) {
      bf16x8 ap = *(const bf16x8*)&p_w[li * 72 + kkh * 32 + g * 8];
#pragma unroll
      for (int ct = 0; ct < 4; ++ct) {
        int d = ct * 16 + li;
        int u2 = (kkh * 4 + g) ^ (d >> 3);
        bf16x8 bv = *(const bf16x8*)&vt_s[d * 72 + u2 * 8];
        oacc[ct] = __builtin_amdgcn_mfma_f32_16x16x32_bf16(ap, bv, oacc[ct], 0, 0, 0);
      }
    }
    __builtin_amdgcn_s_setprio(0);
  }

  // ---- normalize + write ----
#pragma unroll
  for (int ct = 0; ct < 4; ++ct)
#pragma unroll
    for (int r4 = 0; r4 < 4; ++r4) {
      int row = t0 + w * 16 + g * 4 + r4;
      float o = oacc[ct][r4] / lrun[r4];
      attnb[base_bh + (size_t)row * 1024 + ct * 16 + li] = (bf16_t)o;
    }
}

// ---------------- launcher ----------------
extern "C" void kernel_launch(void* const* d_in, const int* in_sizes, int n_in,
                              void* d_out, int out_size, void* d_ws, size_t ws_size,
                              hipStream_t stream) {
  (void)in_sizes; (void)n_in; (void)out_size; (void)ws_size;
  const float* x    = (const float*)d_in[0];
  const float* y    = (const float*)d_in[1];
  const float* mask = (const float*)d_in[2];
  const float* Wq   = (const float*)d_in[3];
  const float* bq   = (const float*)d_in[4];
  const float* Wk   = (const float*)d_in[5];
  const float* bk   = (const float*)d_in[6];
  const float* Wv   = (const float*)d_in[7];
  const float* bv   = (const float*)d_in[8];
  const float* Wp   = (const float*)d_in[9];
  const float* bp   = (const float*)d_in[10];
  const float* rwb  = (const float*)d_in[11];
  const float* rrb  = (const float*)d_in[12];
  const float* Wo   = (const float*)d_in[13];
  const float* bo   = (const float*)d_in[14];
  float* out = (float*)d_out;

  char* ws = (char*)d_ws;
  bf16_t* xb   = (bf16_t*)(ws + 0);            // 8 MB (reused as attnb later)
  bf16_t* yb   = (bf16_t*)(ws + (8ll << 20));
  bf16_t* Wqt  = (bf16_t*)(ws + (16ll << 20));
  bf16_t* Wkt  = (bf16_t*)(ws + (18ll << 20));
  bf16_t* Wvt  = (bf16_t*)(ws + (20ll << 20));
  bf16_t* Wpt  = (bf16_t*)(ws + (22ll << 20));
  bf16_t* Wot  = (bf16_t*)(ws + (24ll << 20));
  bf16_t* sint = (bf16_t*)(ws + (26ll << 20)); // 4 MB
  bf16_t* qwb  = (bf16_t*)(ws + (30ll << 20)); // 8 MB (q + r_w_bias, pre-scaled)
  bf16_t* kbuf = (bf16_t*)(ws + (46ll << 20));
  bf16_t* vbuf = (bf16_t*)(ws + (54ll << 20));
  bf16_t* peb  = (bf16_t*)(ws + (62ll << 20)); // 4 MB
  bf16_t* attnb = xb;                          // alias: x consumed before attn writes

  k_cast_bf16<<<2048, 256, 0, stream>>>(x, xb, 1048576);
  k_cast_bf16<<<2048, 256, 0, stream>>>(y, yb, 1048576);
  dim3 tg(16, 16);
  k_transpose_cast<<<tg, 256, 0, stream>>>(Wq, Wqt);
  k_transpose_cast<<<tg, 256, 0, stream>>>(Wk, Wkt);
  k_transpose_cast<<<tg, 256, 0, stream>>>(Wv, Wvt);
  k_transpose_cast<<<tg, 256, 0, stream>>>(Wp, Wpt);
  k_transpose_cast<<<tg, 256, 0, stream>>>(Wo, Wot);
  k_sinusoid<<<2048, 512, 0, stream>>>(sint);

  dim3 g1(32, 8);  // M=4096
  dim3 g2(16, 8);  // M=2048
  k_gemm<<<g1, 256, 0, stream>>>(xb, Wqt, bq, rwb, QSCALE, qwb, nullptr);
  k_gemm<<<g1, 256, 0, stream>>>(yb, Wkt, bk, nullptr, 1.f, kbuf, nullptr);
  k_gemm<<<g1, 256, 0, stream>>>(yb, Wvt, bv, nullptr, 1.f, vbuf, nullptr);
  k_gemm<<<g2, 256, 0, stream>>>(sint, Wpt, bp, nullptr, 1.f, peb, nullptr);

  dim3 ga(32, 16, 2);
  k_attn<<<ga, 256, 0, stream>>>(qwb, kbuf, vbuf, peb, rwb, rrb, mask, attnb);

  k_gemm<<<g1, 256, 0, stream>>>(attnb, Wot, bo, nullptr, 1.f, nullptr, out);
}

// Round 5
// 381.402 us; speedup vs baseline: 2.0888x; 2.0888x over previous
//
#include <hip/hip_runtime.h>
#include <math.h>

typedef __bf16 bf16_t;
typedef __bf16 bf16x8 __attribute__((ext_vector_type(8)));
typedef __bf16 bf16x4 __attribute__((ext_vector_type(4)));
typedef float  f32x4  __attribute__((ext_vector_type(4)));

#define DEV __device__ __forceinline__

// q pre-scale: 1/sqrt(64) * log2(e), folded into q GEMM epilogue
#define QSCALE 0.18033688011112042f
// 1e10 * log2(e) for the mask penalty (in exp2 domain)
#define MASKF  1.4426950408889634e10f

DEV float fexp2(float x) {
#if __has_builtin(__builtin_amdgcn_exp2f)
  return __builtin_amdgcn_exp2f(x);
#else
  return __expf(x * 0.6931471805599453f);
#endif
}

DEV void gl_lds16(const bf16_t* g, bf16_t* l) {
  __builtin_amdgcn_global_load_lds(
      (const __attribute__((address_space(1))) void*)g,
      (__attribute__((address_space(3))) void*)l, 16, 0, 0);
}

// ---------------- cast f32 -> bf16 (vectorized) ----------------
__global__ void k_cast_bf16(const float* __restrict__ src, bf16_t* __restrict__ dst, int n4) {
  int idx = blockIdx.x * blockDim.x + threadIdx.x;
  int stride = gridDim.x * blockDim.x;
  const float4* s4 = (const float4*)src;
  for (int i = idx; i < n4; i += stride) {
    float4 v = s4[i];
    bf16x4 o;
    o[0] = (bf16_t)v.x; o[1] = (bf16_t)v.y; o[2] = (bf16_t)v.z; o[3] = (bf16_t)v.w;
    *(bf16x4*)(dst + (size_t)i * 4) = o;
  }
}

// ---------------- transpose + cast weight [1024][1024] f32 -> [N][K] bf16 ----------------
__global__ __launch_bounds__(256) void k_transpose_cast(const float* __restrict__ W, bf16_t* __restrict__ Wt) {
  __shared__ float tile[64][65];
  int k0 = blockIdx.x * 64, n0 = blockIdx.y * 64;
  int r = threadIdx.x >> 2;
  int c0 = (threadIdx.x & 3) * 16;
  const float4* src = (const float4*)(W + (size_t)(k0 + r) * 1024 + n0 + c0);
#pragma unroll
  for (int i = 0; i < 4; ++i) {
    float4 v = src[i];
    tile[r][c0 + i * 4 + 0] = v.x;
    tile[r][c0 + i * 4 + 1] = v.y;
    tile[r][c0 + i * 4 + 2] = v.z;
    tile[r][c0 + i * 4 + 3] = v.w;
  }
  __syncthreads();
#pragma unroll
  for (int half = 0; half < 2; ++half) {
    bf16x8 o;
#pragma unroll
    for (int j = 0; j < 8; ++j) o[j] = (bf16_t)tile[c0 + half * 8 + j][r];
    *(bf16x8*)(Wt + (size_t)(n0 + r) * 1024 + k0 + c0 + half * 8) = o;
  }
}

// ---------------- reversed sinusoidal table [2048][1024] bf16 ----------------
__global__ void k_sinusoid(bf16_t* __restrict__ tab) {
  int i = blockIdx.x;   // row
  int d = threadIdx.x;  // 0..511
  float pos = (float)(2047 - i);
  const float coef = (float)(-9.210340371976184 / 511.0);  // -ln(10000)/(n-1)
  float inv = expf((float)d * coef);
  float st = pos * inv;
  tab[(size_t)i * 1024 + d]       = (bf16_t)sinf(st);
  tab[(size_t)i * 1024 + 512 + d] = (bf16_t)cosf(st);
}

// ---------------- GEMM: C[M][1024] = A[M][1024] @ Bt^T, epilogue (acc+bias+eb)*scale ---------
__global__ __launch_bounds__(256) void k_gemm(
    const bf16_t* __restrict__ A, const bf16_t* __restrict__ Bt,
    const float* __restrict__ bias, const float* __restrict__ ebias, float scale,
    bf16_t* __restrict__ outB, float* __restrict__ outF) {
  __shared__ bf16_t As[128 * 64];
  __shared__ bf16_t Bs[128 * 64];
  const int m0 = blockIdx.x * 128, n0 = blockIdx.y * 128;
  const int tid = threadIdx.x;
  const int w = tid >> 6, lane = tid & 63, li = lane & 15, g = lane >> 4;
  const int mb = (w >> 1) * 64, nb = (w & 1) * 64;
  f32x4 acc[4][4] = {};
  for (int kt = 0; kt < 16; ++kt) {
    __syncthreads();
#pragma unroll
    for (int it = 0; it < 4; ++it) {
      int chunk = it * 256 + tid;
      int r = chunk >> 3, kg = chunk & 7;
      gl_lds16(A + (size_t)(m0 + r) * 1024 + kt * 64 + kg * 8, &As[chunk * 8]);
      gl_lds16(Bt + (size_t)(n0 + r) * 1024 + kt * 64 + kg * 8, &Bs[chunk * 8]);
    }
    __syncthreads();
#pragma unroll
    for (int kk = 0; kk < 64; kk += 32) {
      bf16x8 a[4], b[4];
#pragma unroll
      for (int x = 0; x < 4; ++x) {
        a[x] = *(const bf16x8*)&As[(mb + x * 16 + li) * 64 + kk + g * 8];
        b[x] = *(const bf16x8*)&Bs[(nb + x * 16 + li) * 64 + kk + g * 8];
      }
#pragma unroll
      for (int mr = 0; mr < 4; ++mr)
#pragma unroll
        for (int nr = 0; nr < 4; ++nr)
          acc[mr][nr] = __builtin_amdgcn_mfma_f32_16x16x32_bf16(a[mr], b[nr], acc[mr][nr], 0, 0, 0);
    }
  }
#pragma unroll
  for (int mr = 0; mr < 4; ++mr)
#pragma unroll
    for (int nr = 0; nr < 4; ++nr)
#pragma unroll
      for (int r4 = 0; r4 < 4; ++r4) {
        int row = m0 + mb + mr * 16 + g * 4 + r4;
        int col = n0 + nb + nr * 16 + li;
        float v = acc[mr][nr][r4] + bias[col];
        if (ebias) v += ebias[col];
        v *= scale;
        size_t off = (size_t)row * 1024 + col;
        if (outB) outB[off] = (bf16_t)v;
        if (outF) outF[off] = v;
      }
}

// ---------------- fused rel-attention ----------------
// grid (32 tblocks, 16 heads, 2 batch) NATURAL (t fastest: all heads of a
// t-block land on XCD t%8 -> mask shared in L2). 256 threads (4 waves).
// Round-3 structure; pe fragments now staged coalesced into LDS via
// global_load_lds with both-sides XOR chunk swizzle (linear dest, inverse-
// swizzled global source, XOR on read -> ~2-way conflicts = free).
__global__ __launch_bounds__(256, 2) void k_attn(
    const bf16_t* __restrict__ qw, const bf16_t* __restrict__ kb,
    const bf16_t* __restrict__ vb, const bf16_t* __restrict__ peb,
    const float* __restrict__ rwb, const float* __restrict__ rrb,
    const float* __restrict__ mask, bf16_t* __restrict__ attnb) {
  const int t0 = blockIdx.x * 64;
  const int h = blockIdx.y;
  const int b = blockIdx.z;
  const int tid = threadIdx.x;
  const int w = tid >> 6, lane = tid & 63, li = lane & 15, g = lane >> 4;

  __shared__ __align__(16) bf16_t k_s[64 * 72];
  __shared__ __align__(16) bf16_t vt_s[64 * 72];
  __shared__ __align__(16) bf16_t pe_s[2][128 * 64];  // 2 x 16KB windows (A,B)
  __shared__ __align__(16) float R_all[4][16 * 80];
  __shared__ __align__(16) bf16_t p_all[4][16 * 72];

  float* R_w = &R_all[w][0];
  bf16_t* p_w = &p_all[w][0];

  const size_t base_bh = (size_t)b * 2048 * 1024 + (size_t)h * 64;

  // ---- prefetch K/V tile 0 into registers ----
  bf16x8 kpf[2], vpf[2];
#pragma unroll
  for (int it = 0; it < 2; ++it) {
    int c = it * 256 + tid;
    int r = c >> 3, s = c & 7;
    kpf[it] = *(const bf16x8*)(kb + base_bh + (size_t)r * 1024 + s * 8);
    vpf[it] = *(const bf16x8*)(vb + base_bh + (size_t)r * 1024 + s * 8);
  }

  // ---- hoist Q fragments (content + relA + relB) ----
  bf16x8 aq[2], arA[2], arB[2];
  {
    int rowA = t0 + w * 16 + li;
    int rowB = rowA + 1 < 2048 ? rowA + 1 : 2047;
#pragma unroll
    for (int kkh = 0; kkh < 2; ++kkh) {
      int cof = kkh * 32 + g * 8;
      aq[kkh] = *(const bf16x8*)(qw + base_bh + (size_t)rowA * 1024 + cof);
      bf16x8 qb = *(const bf16x8*)(qw + base_bh + (size_t)rowB * 1024 + cof);
#pragma unroll
      for (int j = 0; j < 8; ++j) {
        float dj = (rrb[h * 64 + cof + j] - rwb[h * 64 + cof + j]) * QSCALE;
        arA[kkh][j] = (bf16_t)((float)aq[kkh][j] + dj);
        arB[kkh][j] = (bf16_t)((float)qb[j] + dj);
      }
    }
  }

  float mrun[4], lrun[4];
  f32x4 oacc[4] = {};
#pragma unroll
  for (int r4 = 0; r4 < 4; ++r4) { mrun[r4] = -1e30f; lrun[r4] = 0.f; }

  // pe stage constants: thread covers rows i*32 + (tid>>3), chunk XOR-preswizzled
  const int prow = tid >> 3;                      // 0..31
  const int pchunk = (tid & 7) ^ (prow & 7);      // inverse swizzle on SOURCE

  for (int jt = 0; jt < 32; ++jt) {
    const int j0 = jt * 64;
    const bool actA = (j0 <= t0), actB = (j0 >= t0);
    __syncthreads();  // BAR1: everyone done reading k_s/vt_s/pe_s of prev iter
    // ---- stage K (b128) and V^T (swizzled scalar) from prefetch regs ----
#pragma unroll
    for (int it = 0; it < 2; ++it) {
      int c = it * 256 + tid;
      int r = c >> 3, s = c & 7;
      *(bf16x8*)&k_s[r * 72 + s * 8] = kpf[it];
      int up = ((r >> 3) ^ s);  // unit-XOR swizzle: conflict-free PV reads
#pragma unroll
      for (int dd = 0; dd < 8; ++dd)
        vt_s[(s * 8 + dd) * 72 + up * 8 + (r & 7)] = vpf[it][dd];
    }
    // ---- stage active pe windows (coalesced async DMA; BAR2 drains vmcnt) ----
    if (actA) {
      const int c0 = 1984 + j0 - t0;
#pragma unroll
      for (int i = 0; i < 4; ++i) {
        int rr = i * 32 + prow;
        int c = c0 + rr; c = c < 0 ? 0 : (c > 2047 ? 2047 : c);
        gl_lds16(peb + (size_t)c * 1024 + h * 64 + pchunk * 8,
                 &pe_s[0][rr * 64 + (tid & 7) * 8]);
      }
    }
    if (actB) {
      const int c0 = j0 - t0 - 65;
#pragma unroll
      for (int i = 0; i < 4; ++i) {
        int rr = i * 32 + prow;
        int c = c0 + rr; c = c < 0 ? 0 : (c > 2047 ? 2047 : c);
        gl_lds16(peb + (size_t)c * 1024 + h * 64 + pchunk * 8,
                 &pe_s[1][rr * 64 + (tid & 7) * 8]);
      }
    }
    __syncthreads();  // BAR2: K/V/pe tiles visible
    // ---- prefetch next K/V tile ----
    if (jt < 31) {
#pragma unroll
      for (int it = 0; it < 2; ++it) {
        int c = it * 256 + tid;
        int r = c >> 3, s = c & 7;
        kpf[it] = *(const bf16x8*)(kb + base_bh + (size_t)(j0 + 64 + r) * 1024 + s * 8);
        vpf[it] = *(const bf16x8*)(vb + base_bh + (size_t)(j0 + 64 + r) * 1024 + s * 8);
      }
    }

    // ---- content scores ----
    f32x4 sc[4] = {};
#pragma unroll
    for (int kkh = 0; kkh < 2; ++kkh)
#pragma unroll
      for (int ct = 0; ct < 4; ++ct) {
        bf16x8 bk = *(const bf16x8*)&k_s[(ct * 16 + li) * 72 + kkh * 32 + g * 8];
        sc[ct] = __builtin_amdgcn_mfma_f32_16x16x32_bf16(aq[kkh], bk, sc[ct], 0, 0, 0);
      }

    // ---- relative scores: two Toeplitz cases, per-wave private R band ----
    const int sdc = j0 - t0 - w * 16;
#pragma unroll
    for (int cs = 0; cs < 2; ++cs) {
      if (cs == 0 ? (j0 > t0) : (j0 < t0)) continue;
      f32x4 ra[5] = {};
#pragma unroll
      for (int kkh = 0; kkh < 2; ++kkh) {
        bf16x8 a = cs ? arB[kkh] : arA[kkh];
#pragma unroll
        for (int f = 0; f < 5; ++f) {
          int rr = (3 - w + f) * 16 + li;  // window row, in [0,128)
          const char* pp = (const char*)&pe_s[cs][0] + rr * 128 +
                           ((kkh * 64 + g * 16) ^ ((li & 7) << 4));
          bf16x8 bpv = *(const bf16x8*)pp;
          ra[f] = __builtin_amdgcn_mfma_f32_16x16x32_bf16(a, bpv, ra[f], 0, 0, 0);
        }
      }
#pragma unroll
      for (int f = 0; f < 5; ++f)
#pragma unroll
        for (int r4 = 0; r4 < 4; ++r4)
          R_w[(g * 4 + r4) * 80 + f * 16 + li] = ra[f][r4];
      // wave-private: same-type LDS write->read, compiler orders via lgkmcnt
#pragma unroll
      for (int ct = 0; ct < 4; ++ct)
#pragma unroll
        for (int r4 = 0; r4 < 4; ++r4) {
          int il = g * 4 + r4;
          int col = ct * 16 + li - il + 15;
          float rv = R_w[il * 80 + col];
          int sd = sdc + ct * 16 + li - il;
          bool pr = cs ? (sd >= 2) : (sd <= 0);
          sc[ct][r4] += pr ? rv : 0.f;
        }
    }

    // ---- mask + online softmax (exp2 domain) ----
    float rmax[4] = {-3e38f, -3e38f, -3e38f, -3e38f};
#pragma unroll
    for (int ct = 0; ct < 4; ++ct)
#pragma unroll
      for (int r4 = 0; r4 < 4; ++r4) {
        float mk = mask[((size_t)b * 2048 + t0 + w * 16 + g * 4 + r4) * 2048 + j0 + ct * 16 + li];
        float s = fmaf(mk - 1.f, MASKF, sc[ct][r4]);
        sc[ct][r4] = s;
        rmax[r4] = fmaxf(rmax[r4], s);
      }
#pragma unroll
    for (int r4 = 0; r4 < 4; ++r4)
#pragma unroll
      for (int off = 1; off < 16; off <<= 1)
        rmax[r4] = fmaxf(rmax[r4], __shfl_xor(rmax[r4], off));
    float scl[4], rsum[4];
#pragma unroll
    for (int r4 = 0; r4 < 4; ++r4) {
      float mnew = fmaxf(mrun[r4], rmax[r4]);
      scl[r4] = fexp2(mrun[r4] - mnew);
      mrun[r4] = mnew;
      rsum[r4] = 0.f;
    }
#pragma unroll
    for (int ct = 0; ct < 4; ++ct)
#pragma unroll
      for (int r4 = 0; r4 < 4; ++r4) {
        float p = fexp2(sc[ct][r4] - mrun[r4]);
        sc[ct][r4] = p;
        rsum[r4] += p;
      }
#pragma unroll
    for (int r4 = 0; r4 < 4; ++r4) {
#pragma unroll
      for (int off = 1; off < 16; off <<= 1)
        rsum[r4] += __shfl_xor(rsum[r4], off);
      lrun[r4] = lrun[r4] * scl[r4] + rsum[r4];
    }
#pragma unroll
    for (int ct = 0; ct < 4; ++ct)
#pragma unroll
      for (int r4 = 0; r4 < 4; ++r4) oacc[ct][r4] *= scl[r4];

    // ---- P -> LDS (wave-private buffer) ----
#pragma unroll
    for (int ct = 0; ct < 4; ++ct)
#pragma unroll
      for (int r4 = 0; r4 < 4; ++r4)
        p_w[(g * 4 + r4) * 72 + ct * 16 + li] = (bf16_t)sc[ct][r4];

    // ---- PV ----
#pragma unroll
    for (int kkh = 0; kkh < 2; ++kkh) {
      bf16x8 ap = *(const bf16x8*)&p_w[li * 72 + kkh * 32 + g * 8];
#pragma unroll
      for (int ct = 0; ct < 4; ++ct) {
        int d = ct * 16 + li;
        int u2 = (kkh * 4 + g) ^ (d >> 3);
        bf16x8 bv = *(const bf16x8*)&vt_s[d * 72 + u2 * 8];
        oacc[ct] = __builtin_amdgcn_mfma_f32_16x16x32_bf16(ap, bv, oacc[ct], 0, 0, 0);
      }
    }
  }

  // ---- normalize + write ----
#pragma unroll
  for (int ct = 0; ct < 4; ++ct)
#pragma unroll
    for (int r4 = 0; r4 < 4; ++r4) {
      int row = t0 + w * 16 + g * 4 + r4;
      float o = oacc[ct][r4] / lrun[r4];
      attnb[base_bh + (size_t)row * 1024 + ct * 16 + li] = (bf16_t)o;
    }
}

// ---------------- launcher ----------------
extern "C" void kernel_launch(void* const* d_in, const int* in_sizes, int n_in,
                              void* d_out, int out_size, void* d_ws, size_t ws_size,
                              hipStream_t stream) {
  (void)in_sizes; (void)n_in; (void)out_size; (void)ws_size;
  const float* x    = (const float*)d_in[0];
  const float* y    = (const float*)d_in[1];
  const float* mask = (const float*)d_in[2];
  const float* Wq   = (const float*)d_in[3];
  const float* bq   = (const float*)d_in[4];
  const float* Wk   = (const float*)d_in[5];
  const float* bk   = (const float*)d_in[6];
  const float* Wv   = (const float*)d_in[7];
  const float* bv   = (const float*)d_in[8];
  const float* Wp   = (const float*)d_in[9];
  const float* bp   = (const float*)d_in[10];
  const float* rwb  = (const float*)d_in[11];
  const float* rrb  = (const float*)d_in[12];
  const float* Wo   = (const float*)d_in[13];
  const float* bo   = (const float*)d_in[14];
  float* out = (float*)d_out;

  char* ws = (char*)d_ws;
  bf16_t* xb   = (bf16_t*)(ws + 0);            // 8 MB (reused as attnb later)
  bf16_t* yb   = (bf16_t*)(ws + (8ll << 20));
  bf16_t* Wqt  = (bf16_t*)(ws + (16ll << 20));
  bf16_t* Wkt  = (bf16_t*)(ws + (18ll << 20));
  bf16_t* Wvt  = (bf16_t*)(ws + (20ll << 20));
  bf16_t* Wpt  = (bf16_t*)(ws + (22ll << 20));
  bf16_t* Wot  = (bf16_t*)(ws + (24ll << 20));
  bf16_t* sint = (bf16_t*)(ws + (26ll << 20)); // 4 MB
  bf16_t* qwb  = (bf16_t*)(ws + (30ll << 20)); // 8 MB (q + r_w_bias, pre-scaled)
  bf16_t* kbuf = (bf16_t*)(ws + (46ll << 20));
  bf16_t* vbuf = (bf16_t*)(ws + (54ll << 20));
  bf16_t* peb  = (bf16_t*)(ws + (62ll << 20)); // 4 MB
  bf16_t* attnb = xb;                          // alias: x consumed before attn writes

  k_cast_bf16<<<2048, 256, 0, stream>>>(x, xb, 1048576);
  k_cast_bf16<<<2048, 256, 0, stream>>>(y, yb, 1048576);
  dim3 tg(16, 16);
  k_transpose_cast<<<tg, 256, 0, stream>>>(Wq, Wqt);
  k_transpose_cast<<<tg, 256, 0, stream>>>(Wk, Wkt);
  k_transpose_cast<<<tg, 256, 0, stream>>>(Wv, Wvt);
  k_transpose_cast<<<tg, 256, 0, stream>>>(Wp, Wpt);
  k_transpose_cast<<<tg, 256, 0, stream>>>(Wo, Wot);
  k_sinusoid<<<2048, 512, 0, stream>>>(sint);

  dim3 g1(32, 8);  // M=4096
  dim3 g2(16, 8);  // M=2048
  k_gemm<<<g1, 256, 0, stream>>>(xb, Wqt, bq, rwb, QSCALE, qwb, nullptr);
  k_gemm<<<g1, 256, 0, stream>>>(yb, Wkt, bk, nullptr, 1.f, kbuf, nullptr);
  k_gemm<<<g1, 256, 0, stream>>>(yb, Wvt, bv, nullptr, 1.f, vbuf, nullptr);
  k_gemm<<<g2, 256, 0, stream>>>(sint, Wpt, bp, nullptr, 1.f, peb, nullptr);

  dim3 ga(32, 16, 2);
  k_attn<<<ga, 256, 0, stream>>>(qwb, kbuf, vbuf, peb, rwb, rrb, mask, attnb);

  k_gemm<<<g1, 256, 0, stream>>>(attnb, Wot, bo, nullptr, 1.f, nullptr, out);
}

// Round 6
// 377.650 us; speedup vs baseline: 2.1096x; 1.0099x over previous
//
#include <hip/hip_runtime.h>
#include <math.h>

typedef __bf16 bf16_t;
typedef __bf16 bf16x8 __attribute__((ext_vector_type(8)));
typedef __bf16 bf16x4 __attribute__((ext_vector_type(4)));
typedef float  f32x4  __attribute__((ext_vector_type(4)));

#define DEV __device__ __forceinline__

// q pre-scale: 1/sqrt(64) * log2(e), folded into q GEMM epilogue
#define QSCALE 0.18033688011112042f
// 1e10 * log2(e) for the mask penalty (in exp2 domain)
#define MASKF  1.4426950408889634e10f

DEV float fexp2(float x) {
#if __has_builtin(__builtin_amdgcn_exp2f)
  return __builtin_amdgcn_exp2f(x);
#else
  return __expf(x * 0.6931471805599453f);
#endif
}

DEV void gl_lds16(const bf16_t* g, bf16_t* l) {
  __builtin_amdgcn_global_load_lds(
      (const __attribute__((address_space(1))) void*)g,
      (__attribute__((address_space(3))) void*)l, 16, 0, 0);
}

// ---------------- cast f32 -> bf16 (vectorized) ----------------
__global__ void k_cast_bf16(const float* __restrict__ src, bf16_t* __restrict__ dst, int n4) {
  int idx = blockIdx.x * blockDim.x + threadIdx.x;
  int stride = gridDim.x * blockDim.x;
  const float4* s4 = (const float4*)src;
  for (int i = idx; i < n4; i += stride) {
    float4 v = s4[i];
    bf16x4 o;
    o[0] = (bf16_t)v.x; o[1] = (bf16_t)v.y; o[2] = (bf16_t)v.z; o[3] = (bf16_t)v.w;
    *(bf16x4*)(dst + (size_t)i * 4) = o;
  }
}

// ---------------- transpose + cast weight [1024][1024] f32 -> [N][K] bf16 ----------------
__global__ __launch_bounds__(256) void k_transpose_cast(const float* __restrict__ W, bf16_t* __restrict__ Wt) {
  __shared__ float tile[64][65];
  int k0 = blockIdx.x * 64, n0 = blockIdx.y * 64;
  int r = threadIdx.x >> 2;
  int c0 = (threadIdx.x & 3) * 16;
  const float4* src = (const float4*)(W + (size_t)(k0 + r) * 1024 + n0 + c0);
#pragma unroll
  for (int i = 0; i < 4; ++i) {
    float4 v = src[i];
    tile[r][c0 + i * 4 + 0] = v.x;
    tile[r][c0 + i * 4 + 1] = v.y;
    tile[r][c0 + i * 4 + 2] = v.z;
    tile[r][c0 + i * 4 + 3] = v.w;
  }
  __syncthreads();
#pragma unroll
  for (int half = 0; half < 2; ++half) {
    bf16x8 o;
#pragma unroll
    for (int j = 0; j < 8; ++j) o[j] = (bf16_t)tile[c0 + half * 8 + j][r];
    *(bf16x8*)(Wt + (size_t)(n0 + r) * 1024 + k0 + c0 + half * 8) = o;
  }
}

// ---------------- reversed sinusoidal table [2048][1024] bf16 ----------------
__global__ void k_sinusoid(bf16_t* __restrict__ tab) {
  int i = blockIdx.x;   // row
  int d = threadIdx.x;  // 0..511
  float pos = (float)(2047 - i);
  const float coef = (float)(-9.210340371976184 / 511.0);  // -ln(10000)/(n-1)
  float inv = expf((float)d * coef);
  float st = pos * inv;
  tab[(size_t)i * 1024 + d]       = (bf16_t)sinf(st);
  tab[(size_t)i * 1024 + 512 + d] = (bf16_t)cosf(st);
}

// ---------------- GEMM: C[M][1024] = A[M][1024] @ Bt^T, epilogue (acc+bias+eb)*scale ---------
__global__ __launch_bounds__(256) void k_gemm(
    const bf16_t* __restrict__ A, const bf16_t* __restrict__ Bt,
    const float* __restrict__ bias, const float* __restrict__ ebias, float scale,
    bf16_t* __restrict__ outB, float* __restrict__ outF) {
  __shared__ bf16_t As[128 * 64];
  __shared__ bf16_t Bs[128 * 64];
  const int m0 = blockIdx.x * 128, n0 = blockIdx.y * 128;
  const int tid = threadIdx.x;
  const int w = tid >> 6, lane = tid & 63, li = lane & 15, g = lane >> 4;
  const int mb = (w >> 1) * 64, nb = (w & 1) * 64;
  f32x4 acc[4][4] = {};
  for (int kt = 0; kt < 16; ++kt) {
    __syncthreads();
#pragma unroll
    for (int it = 0; it < 4; ++it) {
      int chunk = it * 256 + tid;
      int r = chunk >> 3, kg = chunk & 7;
      gl_lds16(A + (size_t)(m0 + r) * 1024 + kt * 64 + kg * 8, &As[chunk * 8]);
      gl_lds16(Bt + (size_t)(n0 + r) * 1024 + kt * 64 + kg * 8, &Bs[chunk * 8]);
    }
    __syncthreads();
#pragma unroll
    for (int kk = 0; kk < 64; kk += 32) {
      bf16x8 a[4], b[4];
#pragma unroll
      for (int x = 0; x < 4; ++x) {
        a[x] = *(const bf16x8*)&As[(mb + x * 16 + li) * 64 + kk + g * 8];
        b[x] = *(const bf16x8*)&Bs[(nb + x * 16 + li) * 64 + kk + g * 8];
      }
#pragma unroll
      for (int mr = 0; mr < 4; ++mr)
#pragma unroll
        for (int nr = 0; nr < 4; ++nr)
          acc[mr][nr] = __builtin_amdgcn_mfma_f32_16x16x32_bf16(a[mr], b[nr], acc[mr][nr], 0, 0, 0);
    }
  }
#pragma unroll
  for (int mr = 0; mr < 4; ++mr)
#pragma unroll
    for (int nr = 0; nr < 4; ++nr)
#pragma unroll
      for (int r4 = 0; r4 < 4; ++r4) {
        int row = m0 + mb + mr * 16 + g * 4 + r4;
        int col = n0 + nb + nr * 16 + li;
        float v = acc[mr][nr][r4] + bias[col];
        if (ebias) v += ebias[col];
        v *= scale;
        size_t off = (size_t)row * 1024 + col;
        if (outB) outB[off] = (bf16_t)v;
        if (outF) outF[off] = v;
      }
}

// ---------------- fused rel-attention ----------------
// grid 1024 linear, pair-XCD swizzle: each XCD owns 4 complete (b,h) pairs
// (all 32 t-blocks of a pair on ONE XCD -> K/V stream L2-resident; mask is
// L3-resident, pair-shared in L2). Body identical to round-5 passing version.
__global__ __launch_bounds__(256, 2) void k_attn(
    const bf16_t* __restrict__ qw, const bf16_t* __restrict__ kb,
    const bf16_t* __restrict__ vb, const bf16_t* __restrict__ peb,
    const float* __restrict__ rwb, const float* __restrict__ rrb,
    const float* __restrict__ mask, bf16_t* __restrict__ attnb) {
  const int orig = blockIdx.x;
  const int xcd  = orig & 7;
  const int idx  = orig >> 3;            // 0..127
  const int pair = xcd * 4 + (idx >> 5); // 0..31, 4 pairs per XCD
  const int t0   = (idx & 31) * 64;
  const int h    = pair & 15;
  const int b    = pair >> 4;
  const int tid = threadIdx.x;
  const int w = tid >> 6, lane = tid & 63, li = lane & 15, g = lane >> 4;

  __shared__ __align__(16) bf16_t k_s[64 * 72];
  __shared__ __align__(16) bf16_t vt_s[64 * 72];
  __shared__ __align__(16) bf16_t pe_s[2][128 * 64];  // 2 x 16KB windows (A,B)
  __shared__ __align__(16) float R_all[4][16 * 80];
  __shared__ __align__(16) bf16_t p_all[4][16 * 72];

  float* R_w = &R_all[w][0];
  bf16_t* p_w = &p_all[w][0];

  const size_t base_bh = (size_t)b * 2048 * 1024 + (size_t)h * 64;

  // ---- prefetch K/V tile 0 into registers ----
  bf16x8 kpf[2], vpf[2];
#pragma unroll
  for (int it = 0; it < 2; ++it) {
    int c = it * 256 + tid;
    int r = c >> 3, s = c & 7;
    kpf[it] = *(const bf16x8*)(kb + base_bh + (size_t)r * 1024 + s * 8);
    vpf[it] = *(const bf16x8*)(vb + base_bh + (size_t)r * 1024 + s * 8);
  }

  // ---- hoist Q fragments (content + relA + relB) ----
  bf16x8 aq[2], arA[2], arB[2];
  {
    int rowA = t0 + w * 16 + li;
    int rowB = rowA + 1 < 2048 ? rowA + 1 : 2047;
#pragma unroll
    for (int kkh = 0; kkh < 2; ++kkh) {
      int cof = kkh * 32 + g * 8;
      aq[kkh] = *(const bf16x8*)(qw + base_bh + (size_t)rowA * 1024 + cof);
      bf16x8 qb = *(const bf16x8*)(qw + base_bh + (size_t)rowB * 1024 + cof);
#pragma unroll
      for (int j = 0; j < 8; ++j) {
        float dj = (rrb[h * 64 + cof + j] - rwb[h * 64 + cof + j]) * QSCALE;
        arA[kkh][j] = (bf16_t)((float)aq[kkh][j] + dj);
        arB[kkh][j] = (bf16_t)((float)qb[j] + dj);
      }
    }
  }

  float mrun[4], lrun[4];
  f32x4 oacc[4] = {};
#pragma unroll
  for (int r4 = 0; r4 < 4; ++r4) { mrun[r4] = -1e30f; lrun[r4] = 0.f; }

  // pe stage constants: thread covers rows i*32 + (tid>>3), chunk XOR-preswizzled
  const int prow = tid >> 3;                      // 0..31
  const int pchunk = (tid & 7) ^ (prow & 7);      // inverse swizzle on SOURCE

  for (int jt = 0; jt < 32; ++jt) {
    const int j0 = jt * 64;
    const bool actA = (j0 <= t0), actB = (j0 >= t0);
    __syncthreads();  // BAR1: everyone done reading k_s/vt_s/pe_s of prev iter
    // ---- stage K (b128) and V^T (swizzled scalar) from prefetch regs ----
#pragma unroll
    for (int it = 0; it < 2; ++it) {
      int c = it * 256 + tid;
      int r = c >> 3, s = c & 7;
      *(bf16x8*)&k_s[r * 72 + s * 8] = kpf[it];
      int up = ((r >> 3) ^ s);  // unit-XOR swizzle: conflict-free PV reads
#pragma unroll
      for (int dd = 0; dd < 8; ++dd)
        vt_s[(s * 8 + dd) * 72 + up * 8 + (r & 7)] = vpf[it][dd];
    }
    // ---- stage active pe windows (coalesced async DMA; BAR2 drains vmcnt) ----
    if (actA) {
      const int c0 = 1984 + j0 - t0;
#pragma unroll
      for (int i = 0; i < 4; ++i) {
        int rr = i * 32 + prow;
        int c = c0 + rr; c = c < 0 ? 0 : (c > 2047 ? 2047 : c);
        gl_lds16(peb + (size_t)c * 1024 + h * 64 + pchunk * 8,
                 &pe_s[0][rr * 64 + (tid & 7) * 8]);
      }
    }
    if (actB) {
      const int c0 = j0 - t0 - 65;
#pragma unroll
      for (int i = 0; i < 4; ++i) {
        int rr = i * 32 + prow;
        int c = c0 + rr; c = c < 0 ? 0 : (c > 2047 ? 2047 : c);
        gl_lds16(peb + (size_t)c * 1024 + h * 64 + pchunk * 8,
                 &pe_s[1][rr * 64 + (tid & 7) * 8]);
      }
    }
    __syncthreads();  // BAR2: K/V/pe tiles visible
    // ---- prefetch next K/V tile ----
    if (jt < 31) {
#pragma unroll
      for (int it = 0; it < 2; ++it) {
        int c = it * 256 + tid;
        int r = c >> 3, s = c & 7;
        kpf[it] = *(const bf16x8*)(kb + base_bh + (size_t)(j0 + 64 + r) * 1024 + s * 8);
        vpf[it] = *(const bf16x8*)(vb + base_bh + (size_t)(j0 + 64 + r) * 1024 + s * 8);
      }
    }

    // ---- content scores ----
    f32x4 sc[4] = {};
#pragma unroll
    for (int kkh = 0; kkh < 2; ++kkh)
#pragma unroll
      for (int ct = 0; ct < 4; ++ct) {
        bf16x8 bk = *(const bf16x8*)&k_s[(ct * 16 + li) * 72 + kkh * 32 + g * 8];
        sc[ct] = __builtin_amdgcn_mfma_f32_16x16x32_bf16(aq[kkh], bk, sc[ct], 0, 0, 0);
      }

    // ---- relative scores: two Toeplitz cases, per-wave private R band ----
    const int sdc = j0 - t0 - w * 16;
#pragma unroll
    for (int cs = 0; cs < 2; ++cs) {
      if (cs == 0 ? (j0 > t0) : (j0 < t0)) continue;
      f32x4 ra[5] = {};
#pragma unroll
      for (int kkh = 0; kkh < 2; ++kkh) {
        bf16x8 a = cs ? arB[kkh] : arA[kkh];
#pragma unroll
        for (int f = 0; f < 5; ++f) {
          int rr = (3 - w + f) * 16 + li;  // window row, in [0,128)
          const char* pp = (const char*)&pe_s[cs][0] + rr * 128 +
                           ((kkh * 64 + g * 16) ^ ((li & 7) << 4));
          bf16x8 bpv = *(const bf16x8*)pp;
          ra[f] = __builtin_amdgcn_mfma_f32_16x16x32_bf16(a, bpv, ra[f], 0, 0, 0);
        }
      }
#pragma unroll
      for (int f = 0; f < 5; ++f)
#pragma unroll
        for (int r4 = 0; r4 < 4; ++r4)
          R_w[(g * 4 + r4) * 80 + f * 16 + li] = ra[f][r4];
      // wave-private: same-type LDS write->read, compiler orders via lgkmcnt
#pragma unroll
      for (int ct = 0; ct < 4; ++ct)
#pragma unroll
        for (int r4 = 0; r4 < 4; ++r4) {
          int il = g * 4 + r4;
          int col = ct * 16 + li - il + 15;
          float rv = R_w[il * 80 + col];
          int sd = sdc + ct * 16 + li - il;
          bool pr = cs ? (sd >= 2) : (sd <= 0);
          sc[ct][r4] += pr ? rv : 0.f;
        }
    }

    // ---- mask + online softmax (exp2 domain) ----
    float rmax[4] = {-3e38f, -3e38f, -3e38f, -3e38f};
#pragma unroll
    for (int ct = 0; ct < 4; ++ct)
#pragma unroll
      for (int r4 = 0; r4 < 4; ++r4) {
        float mk = mask[((size_t)b * 2048 + t0 + w * 16 + g * 4 + r4) * 2048 + j0 + ct * 16 + li];
        float s = fmaf(mk - 1.f, MASKF, sc[ct][r4]);
        sc[ct][r4] = s;
        rmax[r4] = fmaxf(rmax[r4], s);
      }
#pragma unroll
    for (int r4 = 0; r4 < 4; ++r4)
#pragma unroll
      for (int off = 1; off < 16; off <<= 1)
        rmax[r4] = fmaxf(rmax[r4], __shfl_xor(rmax[r4], off));
    float scl[4], rsum[4];
#pragma unroll
    for (int r4 = 0; r4 < 4; ++r4) {
      float mnew = fmaxf(mrun[r4], rmax[r4]);
      scl[r4] = fexp2(mrun[r4] - mnew);
      mrun[r4] = mnew;
      rsum[r4] = 0.f;
    }
#pragma unroll
    for (int ct = 0; ct < 4; ++ct)
#pragma unroll
      for (int r4 = 0; r4 < 4; ++r4) {
        float p = fexp2(sc[ct][r4] - mrun[r4]);
        sc[ct][r4] = p;
        rsum[r4] += p;
      }
#pragma unroll
    for (int r4 = 0; r4 < 4; ++r4) {
#pragma unroll
      for (int off = 1; off < 16; off <<= 1)
        rsum[r4] += __shfl_xor(rsum[r4], off);
      lrun[r4] = lrun[r4] * scl[r4] + rsum[r4];
    }
#pragma unroll
    for (int ct = 0; ct < 4; ++ct)
#pragma unroll
      for (int r4 = 0; r4 < 4; ++r4) oacc[ct][r4] *= scl[r4];

    // ---- P -> LDS (wave-private buffer) ----
#pragma unroll
    for (int ct = 0; ct < 4; ++ct)
#pragma unroll
      for (int r4 = 0; r4 < 4; ++r4)
        p_w[(g * 4 + r4) * 72 + ct * 16 + li] = (bf16_t)sc[ct][r4];

    // ---- PV ----
#pragma unroll
    for (int kkh = 0; kkh < 2; ++kkh) {
      bf16x8 ap = *(const bf16x8*)&p_w[li * 72 + kkh * 32 + g * 8];
#pragma unroll
      for (int ct = 0; ct < 4; ++ct) {
        int d = ct * 16 + li;
        int u2 = (kkh * 4 + g) ^ (d >> 3);
        bf16x8 bv = *(const bf16x8*)&vt_s[d * 72 + u2 * 8];
        oacc[ct] = __builtin_amdgcn_mfma_f32_16x16x32_bf16(ap, bv, oacc[ct], 0, 0, 0);
      }
    }
  }

  // ---- normalize + write ----
#pragma unroll
  for (int ct = 0; ct < 4; ++ct)
#pragma unroll
    for (int r4 = 0; r4 < 4; ++r4) {
      int row = t0 + w * 16 + g * 4 + r4;
      float o = oacc[ct][r4] / lrun[r4];
      attnb[base_bh + (size_t)row * 1024 + ct * 16 + li] = (bf16_t)o;
    }
}

// ---------------- launcher ----------------
extern "C" void kernel_launch(void* const* d_in, const int* in_sizes, int n_in,
                              void* d_out, int out_size, void* d_ws, size_t ws_size,
                              hipStream_t stream) {
  (void)in_sizes; (void)n_in; (void)out_size; (void)ws_size;
  const float* x    = (const float*)d_in[0];
  const float* y    = (const float*)d_in[1];
  const float* mask = (const float*)d_in[2];
  const float* Wq   = (const float*)d_in[3];
  const float* bq   = (const float*)d_in[4];
  const float* Wk   = (const float*)d_in[5];
  const float* bk   = (const float*)d_in[6];
  const float* Wv   = (const float*)d_in[7];
  const float* bv   = (const float*)d_in[8];
  const float* Wp   = (const float*)d_in[9];
  const float* bp   = (const float*)d_in[10];
  const float* rwb  = (const float*)d_in[11];
  const float* rrb  = (const float*)d_in[12];
  const float* Wo   = (const float*)d_in[13];
  const float* bo   = (const float*)d_in[14];
  float* out = (float*)d_out;

  char* ws = (char*)d_ws;
  bf16_t* xb   = (bf16_t*)(ws + 0);            // 8 MB (reused as attnb later)
  bf16_t* yb   = (bf16_t*)(ws + (8ll << 20));
  bf16_t* Wqt  = (bf16_t*)(ws + (16ll << 20));
  bf16_t* Wkt  = (bf16_t*)(ws + (18ll << 20));
  bf16_t* Wvt  = (bf16_t*)(ws + (20ll << 20));
  bf16_t* Wpt  = (bf16_t*)(ws + (22ll << 20));
  bf16_t* Wot  = (bf16_t*)(ws + (24ll << 20));
  bf16_t* sint = (bf16_t*)(ws + (26ll << 20)); // 4 MB
  bf16_t* qwb  = (bf16_t*)(ws + (30ll << 20)); // 8 MB (q + r_w_bias, pre-scaled)
  bf16_t* kbuf = (bf16_t*)(ws + (46ll << 20));
  bf16_t* vbuf = (bf16_t*)(ws + (54ll << 20));
  bf16_t* peb  = (bf16_t*)(ws + (62ll << 20)); // 4 MB
  bf16_t* attnb = xb;                          // alias: x consumed before attn writes

  k_cast_bf16<<<2048, 256, 0, stream>>>(x, xb, 1048576);
  k_cast_bf16<<<2048, 256, 0, stream>>>(y, yb, 1048576);
  dim3 tg(16, 16);
  k_transpose_cast<<<tg, 256, 0, stream>>>(Wq, Wqt);
  k_transpose_cast<<<tg, 256, 0, stream>>>(Wk, Wkt);
  k_transpose_cast<<<tg, 256, 0, stream>>>(Wv, Wvt);
  k_transpose_cast<<<tg, 256, 0, stream>>>(Wp, Wpt);
  k_transpose_cast<<<tg, 256, 0, stream>>>(Wo, Wot);
  k_sinusoid<<<2048, 512, 0, stream>>>(sint);

  dim3 g1(32, 8);  // M=4096
  dim3 g2(16, 8);  // M=2048
  k_gemm<<<g1, 256, 0, stream>>>(xb, Wqt, bq, rwb, QSCALE, qwb, nullptr);
  k_gemm<<<g1, 256, 0, stream>>>(yb, Wkt, bk, nullptr, 1.f, kbuf, nullptr);
  k_gemm<<<g1, 256, 0, stream>>>(yb, Wvt, bv, nullptr, 1.f, vbuf, nullptr);
  k_gemm<<<g2, 256, 0, stream>>>(sint, Wpt, bp, nullptr, 1.f, peb, nullptr);

  k_attn<<<1024, 256, 0, stream>>>(qwb, kbuf, vbuf, peb, rwb, rrb, mask, attnb);

  k_gemm<<<g1, 256, 0, stream>>>(attnb, Wot, bo, nullptr, 1.f, nullptr, out);
}

// Round 7
// 364.653 us; speedup vs baseline: 2.1848x; 1.0356x over previous
//
#include <hip/hip_runtime.h>
#include <math.h>

typedef __bf16 bf16_t;
typedef __bf16 bf16x8 __attribute__((ext_vector_type(8)));
typedef __bf16 bf16x4 __attribute__((ext_vector_type(4)));
typedef float  f32x4  __attribute__((ext_vector_type(4)));

#define DEV __device__ __forceinline__

// q pre-scale: 1/sqrt(64) * log2(e), folded into q GEMM epilogue
#define QSCALE 0.18033688011112042f
// 1e10 * log2(e) for the mask penalty (in exp2 domain)
#define MASKF  1.4426950408889634e10f

DEV float fexp2(float x) {
#if __has_builtin(__builtin_amdgcn_exp2f)
  return __builtin_amdgcn_exp2f(x);
#else
  return __expf(x * 0.6931471805599453f);
#endif
}

DEV void gl_lds16(const bf16_t* g, bf16_t* l) {
  __builtin_amdgcn_global_load_lds(
      (const __attribute__((address_space(1))) void*)g,
      (__attribute__((address_space(3))) void*)l, 16, 0, 0);
}

DEV int clamp2047(int c) { return c < 0 ? 0 : (c > 2047 ? 2047 : c); }

// ---------------- cast f32 -> bf16 (vectorized) ----------------
__global__ void k_cast_bf16(const float* __restrict__ src, bf16_t* __restrict__ dst, int n4) {
  int idx = blockIdx.x * blockDim.x + threadIdx.x;
  int stride = gridDim.x * blockDim.x;
  const float4* s4 = (const float4*)src;
  for (int i = idx; i < n4; i += stride) {
    float4 v = s4[i];
    bf16x4 o;
    o[0] = (bf16_t)v.x; o[1] = (bf16_t)v.y; o[2] = (bf16_t)v.z; o[3] = (bf16_t)v.w;
    *(bf16x4*)(dst + (size_t)i * 4) = o;
  }
}

// ---------------- transpose + cast weight [1024][1024] f32 -> [N][K] bf16 ----------------
__global__ __launch_bounds__(256) void k_transpose_cast(const float* __restrict__ W, bf16_t* __restrict__ Wt) {
  __shared__ float tile[64][65];
  int k0 = blockIdx.x * 64, n0 = blockIdx.y * 64;
  int r = threadIdx.x >> 2;
  int c0 = (threadIdx.x & 3) * 16;
  const float4* src = (const float4*)(W + (size_t)(k0 + r) * 1024 + n0 + c0);
#pragma unroll
  for (int i = 0; i < 4; ++i) {
    float4 v = src[i];
    tile[r][c0 + i * 4 + 0] = v.x;
    tile[r][c0 + i * 4 + 1] = v.y;
    tile[r][c0 + i * 4 + 2] = v.z;
    tile[r][c0 + i * 4 + 3] = v.w;
  }
  __syncthreads();
#pragma unroll
  for (int half = 0; half < 2; ++half) {
    bf16x8 o;
#pragma unroll
    for (int j = 0; j < 8; ++j) o[j] = (bf16_t)tile[c0 + half * 8 + j][r];
    *(bf16x8*)(Wt + (size_t)(n0 + r) * 1024 + k0 + c0 + half * 8) = o;
  }
}

// ---------------- reversed sinusoidal table [2048][1024] bf16 ----------------
__global__ void k_sinusoid(bf16_t* __restrict__ tab) {
  int i = blockIdx.x;   // row
  int d = threadIdx.x;  // 0..511
  float pos = (float)(2047 - i);
  const float coef = (float)(-9.210340371976184 / 511.0);  // -ln(10000)/(n-1)
  float inv = expf((float)d * coef);
  float st = pos * inv;
  tab[(size_t)i * 1024 + d]       = (bf16_t)sinf(st);
  tab[(size_t)i * 1024 + 512 + d] = (bf16_t)cosf(st);
}

// ---------------- GEMM: C[M][1024] = A[M][1024] @ Bt^T, epilogue (acc+bias+eb)*scale ---------
__global__ __launch_bounds__(256) void k_gemm(
    const bf16_t* __restrict__ A, const bf16_t* __restrict__ Bt,
    const float* __restrict__ bias, const float* __restrict__ ebias, float scale,
    bf16_t* __restrict__ outB, float* __restrict__ outF) {
  __shared__ bf16_t As[128 * 64];
  __shared__ bf16_t Bs[128 * 64];
  const int m0 = blockIdx.x * 128, n0 = blockIdx.y * 128;
  const int tid = threadIdx.x;
  const int w = tid >> 6, lane = tid & 63, li = lane & 15, g = lane >> 4;
  const int mb = (w >> 1) * 64, nb = (w & 1) * 64;
  f32x4 acc[4][4] = {};
  for (int kt = 0; kt < 16; ++kt) {
    __syncthreads();
#pragma unroll
    for (int it = 0; it < 4; ++it) {
      int chunk = it * 256 + tid;
      int r = chunk >> 3, kg = chunk & 7;
      gl_lds16(A + (size_t)(m0 + r) * 1024 + kt * 64 + kg * 8, &As[chunk * 8]);
      gl_lds16(Bt + (size_t)(n0 + r) * 1024 + kt * 64 + kg * 8, &Bs[chunk * 8]);
    }
    __syncthreads();
#pragma unroll
    for (int kk = 0; kk < 64; kk += 32) {
      bf16x8 a[4], b[4];
#pragma unroll
      for (int x = 0; x < 4; ++x) {
        a[x] = *(const bf16x8*)&As[(mb + x * 16 + li) * 64 + kk + g * 8];
        b[x] = *(const bf16x8*)&Bs[(nb + x * 16 + li) * 64 + kk + g * 8];
      }
#pragma unroll
      for (int mr = 0; mr < 4; ++mr)
#pragma unroll
        for (int nr = 0; nr < 4; ++nr)
          acc[mr][nr] = __builtin_amdgcn_mfma_f32_16x16x32_bf16(a[mr], b[nr], acc[mr][nr], 0, 0, 0);
    }
  }
#pragma unroll
  for (int mr = 0; mr < 4; ++mr)
#pragma unroll
    for (int nr = 0; nr < 4; ++nr)
#pragma unroll
      for (int r4 = 0; r4 < 4; ++r4) {
        int row = m0 + mb + mr * 16 + g * 4 + r4;
        int col = n0 + nb + nr * 16 + li;
        float v = acc[mr][nr][r4] + bias[col];
        if (ebias) v += ebias[col];
        v *= scale;
        size_t off = (size_t)row * 1024 + col;
        if (outB) outB[off] = (bf16_t)v;
        if (outF) outF[off] = v;
      }
}

// ---------------- fused rel-attention ----------------
// grid 1024, pair-XCD swizzle. 256 threads (4 waves), 64 q-rows / WG.
// Chain-shortening structure:
//  - pe: 2-slot parity ring per case, global->reg prefetch one iter ahead,
//    reg->LDS at the barrier-synced stage phase (no VMEM drain at BAR2).
//    Case B window shifted +1 to 64-alignment; its single outside row handled
//    by a broadcast global load (w==3, f==0, lane li==0 only).
//  - rel band gather: in-register ds_bpermute shuffle (no R LDS round-trip).
//  - mask: register-prefetched one iteration ahead.
__global__ __launch_bounds__(256, 2) void k_attn(
    const bf16_t* __restrict__ qw, const bf16_t* __restrict__ kb,
    const bf16_t* __restrict__ vb, const bf16_t* __restrict__ peb,
    const float* __restrict__ rwb, const float* __restrict__ rrb,
    const float* __restrict__ mask, bf16_t* __restrict__ attnb) {
  const int orig = blockIdx.x;
  const int xcd  = orig & 7;
  const int idx  = orig >> 3;            // 0..127
  const int pair = xcd * 4 + (idx >> 5); // 0..31, 4 pairs per XCD
  const int t0   = (idx & 31) * 64;
  const int h    = pair & 15;
  const int b    = pair >> 4;
  const int tid = threadIdx.x;
  const int w = tid >> 6, lane = tid & 63, li = lane & 15, g = lane >> 4;

  __shared__ __align__(16) bf16_t k_s[64 * 72];
  __shared__ __align__(16) bf16_t vt_s[64 * 72];
  __shared__ __align__(16) bf16_t peA_s[2 * 64 * 64];  // 2-slot ring, case A
  __shared__ __align__(16) bf16_t peB_s[2 * 64 * 64];  // 2-slot ring, case B
  __shared__ __align__(16) bf16_t p_all[4][16 * 72];

  bf16_t* p_w = &p_all[w][0];

  const size_t base_bh = (size_t)b * 2048 * 1024 + (size_t)h * 64;

  const int tq  = t0 >> 6;
  const int nA0 = 31 - tq;   // first A chunk (window [1984-t0, +128) at jt=0)
  const int mB0 = -tq - 1;   // first B chunk (aligned window [j0-t0-64, +128))

  // per-thread stage geometry: slot index si covers (row r, 16B col-chunk cc)
  // LDS[r][cc] holds global col-chunk cc ^ (r&7)  (XOR swizzle, both sides)

  // ---- prologue: DMA chunks nA0 / mB0 (linear dest, pre-swizzled source) ----
#pragma unroll
  for (int p = 0; p < 2; ++p) {
    int si = p * 256 + tid;
    int r = si >> 3, cc = si & 7, ccs = cc ^ (r & 7);
    int ca = clamp2047(nA0 * 64 + r);
    gl_lds16(peb + (size_t)ca * 1024 + h * 64 + ccs * 8, &peA_s[(nA0 & 1) * 4096 + si * 8]);
    int cb = clamp2047(mB0 * 64 + r);
    gl_lds16(peb + (size_t)cb * 1024 + h * 64 + ccs * 8, &peB_s[(mB0 & 1) * 4096 + si * 8]);
  }
  // ---- prologue: reg-prefetch chunks nA0+1 / mB0+1 (staged at iter 0) ----
  bf16x8 pra[2], prb[2];
#pragma unroll
  for (int p = 0; p < 2; ++p) {
    int si = p * 256 + tid;
    int r = si >> 3, cc = si & 7;
    int ca = clamp2047((nA0 + 1) * 64 + r);
    pra[p] = *(const bf16x8*)(peb + (size_t)ca * 1024 + h * 64 + cc * 8);
    int cb = clamp2047((mB0 + 1) * 64 + r);
    prb[p] = *(const bf16x8*)(peb + (size_t)cb * 1024 + h * 64 + cc * 8);
  }

  // ---- prefetch K/V tile 0 into registers ----
  bf16x8 kpf[2], vpf[2];
#pragma unroll
  for (int it = 0; it < 2; ++it) {
    int c = it * 256 + tid;
    int r = c >> 3, s = c & 7;
    kpf[it] = *(const bf16x8*)(kb + base_bh + (size_t)r * 1024 + s * 8);
    vpf[it] = *(const bf16x8*)(vb + base_bh + (size_t)r * 1024 + s * 8);
  }

  // ---- hoist Q fragments (content + relA + relB) ----
  bf16x8 aq[2], arA[2], arB[2];
  {
    int rowA = t0 + w * 16 + li;
    int rowB = rowA + 1 < 2048 ? rowA + 1 : 2047;
#pragma unroll
    for (int kkh = 0; kkh < 2; ++kkh) {
      int cof = kkh * 32 + g * 8;
      aq[kkh] = *(const bf16x8*)(qw + base_bh + (size_t)rowA * 1024 + cof);
      bf16x8 qb = *(const bf16x8*)(qw + base_bh + (size_t)rowB * 1024 + cof);
#pragma unroll
      for (int j = 0; j < 8; ++j) {
        float dj = (rrb[h * 64 + cof + j] - rwb[h * 64 + cof + j]) * QSCALE;
        arA[kkh][j] = (bf16_t)((float)aq[kkh][j] + dj);
        arB[kkh][j] = (bf16_t)((float)qb[j] + dj);
      }
    }
  }

  // ---- prologue: mask tile for jt=0 ----
  float mpf[4][4];
#pragma unroll
  for (int ct = 0; ct < 4; ++ct)
#pragma unroll
    for (int r4 = 0; r4 < 4; ++r4)
      mpf[ct][r4] = mask[((size_t)b * 2048 + t0 + w * 16 + g * 4 + r4) * 2048 + ct * 16 + li];

  float mrun[4], lrun[4];
  f32x4 oacc[4] = {};
#pragma unroll
  for (int r4 = 0; r4 < 4; ++r4) { mrun[r4] = -1e30f; lrun[r4] = 0.f; }

  for (int jt = 0; jt < 32; ++jt) {
    const int j0 = jt * 64;
    __syncthreads();  // BAR1: all reads of prev iter's LDS done
    // ---- stage K (b128) and V^T (swizzled scalar) from prefetch regs ----
#pragma unroll
    for (int it = 0; it < 2; ++it) {
      int c = it * 256 + tid;
      int r = c >> 3, s = c & 7;
      *(bf16x8*)&k_s[r * 72 + s * 8] = kpf[it];
      int up = ((r >> 3) ^ s);  // unit-XOR swizzle: conflict-free PV reads
#pragma unroll
      for (int dd = 0; dd < 8; ++dd)
        vt_s[(s * 8 + dd) * 72 + up * 8 + (r & 7)] = vpf[it][dd];
    }
    // ---- stage pe chunks (regs -> ring slot; barrier-ordered, no vm drain) ----
    {
      const int CNa = nA0 + jt + 1, CNb = mB0 + jt + 1;
#pragma unroll
      for (int p = 0; p < 2; ++p) {
        int si = p * 256 + tid;
        int r = si >> 3, cc = si & 7;
        int eo = (cc ^ (r & 7)) << 3;
        *(bf16x8*)&peA_s[(CNa & 1) * 4096 + r * 64 + eo] = pra[p];
        *(bf16x8*)&peB_s[(CNb & 1) * 4096 + r * 64 + eo] = prb[p];
      }
    }
    __syncthreads();  // BAR2: tiles visible (LDS-only drain)

    // ---- prefetch next K/V tile ----
    if (jt < 31) {
#pragma unroll
      for (int it = 0; it < 2; ++it) {
        int c = it * 256 + tid;
        int r = c >> 3, s = c & 7;
        kpf[it] = *(const bf16x8*)(kb + base_bh + (size_t)(j0 + 64 + r) * 1024 + s * 8);
        vpf[it] = *(const bf16x8*)(vb + base_bh + (size_t)(j0 + 64 + r) * 1024 + s * 8);
      }
    }
    // ---- prefetch pe chunks +2 (staged next iter) ----
#pragma unroll
    for (int p = 0; p < 2; ++p) {
      int si = p * 256 + tid;
      int r = si >> 3, cc = si & 7;
      int ca = clamp2047((nA0 + jt + 2) * 64 + r);
      pra[p] = *(const bf16x8*)(peb + (size_t)ca * 1024 + h * 64 + cc * 8);
      int cb = clamp2047((mB0 + jt + 2) * 64 + r);
      prb[p] = *(const bf16x8*)(peb + (size_t)cb * 1024 + h * 64 + cc * 8);
    }
    // ---- prefetch next mask tile ----
    float mnext[4][4];
    {
      int j0n = j0 + 64; if (j0n > 1984) j0n = 1984;
#pragma unroll
      for (int ct = 0; ct < 4; ++ct)
#pragma unroll
        for (int r4 = 0; r4 < 4; ++r4)
          mnext[ct][r4] = mask[((size_t)b * 2048 + t0 + w * 16 + g * 4 + r4) * 2048 + j0n + ct * 16 + li];
    }

    // ---- content scores ----
    f32x4 sc[4] = {};
#pragma unroll
    for (int kkh = 0; kkh < 2; ++kkh)
#pragma unroll
      for (int ct = 0; ct < 4; ++ct) {
        bf16x8 bk = *(const bf16x8*)&k_s[(ct * 16 + li) * 72 + kkh * 32 + g * 8];
        sc[ct] = __builtin_amdgcn_mfma_f32_16x16x32_bf16(aq[kkh], bk, sc[ct], 0, 0, 0);
      }

    // ---- relative scores: two Toeplitz cases from pe rings ----
    const int sdc = j0 - t0 - w * 16;
#pragma unroll
    for (int cs = 0; cs < 2; ++cs) {
      if (cs == 0 ? (j0 > t0) : (j0 < t0)) continue;
      const int c0 = cs ? (j0 - t0 - 65) : (1984 + j0 - t0);
      const char* ring = (const char*)(cs ? peB_s : peA_s);
      f32x4 ra[5] = {};
#pragma unroll
      for (int kkh = 0; kkh < 2; ++kkh) {
        bf16x8 a = cs ? arB[kkh] : arA[kkh];
#pragma unroll
        for (int f = 0; f < 5; ++f) {
          int c = c0 + (3 - w + f) * 16 + li;
          int slot = (c >> 6) & 1, rin = c & 63;
          bf16x8 bpv = *(const bf16x8*)(ring + slot * 8192 + rin * 128 +
                                        ((kkh * 64 + g * 16) ^ ((c & 7) << 4)));
          if (cs == 1 && f == 0) {
            if (w == 3) {  // lane li==0 needs the one row outside the aligned window
              int cg = clamp2047(c0);
              bf16x8 vg = *(const bf16x8*)(peb + (size_t)cg * 1024 + h * 64 + kkh * 32 + g * 8);
              if (li == 0) bpv = vg;
            }
          }
          ra[f] = __builtin_amdgcn_mfma_f32_16x16x32_bf16(a, bpv, ra[f], 0, 0, 0);
        }
      }
      // in-register band gather (replaces R LDS round-trip):
      // reader (li, il=g*4+r4) needs ra[f'][r4] from lane (g, (li-il+15)&15),
      // f' = ct + (li>il). Same g-group, same register slot r4.
#pragma unroll
      for (int r4 = 0; r4 < 4; ++r4) {
        const int il = g * 4 + r4;
        const int srcLane = (lane & 48) | ((li - il + 15) & 15);
        float sh[5];
#pragma unroll
        for (int f = 0; f < 5; ++f) sh[f] = __shfl(ra[f][r4], srcLane, 64);
#pragma unroll
        for (int ct = 0; ct < 4; ++ct) {
          float rv = (li > il) ? sh[ct + 1] : sh[ct];
          int sd = sdc + ct * 16 + li - il;
          bool pr = cs ? (sd >= 2) : (sd <= 0);
          sc[ct][r4] += pr ? rv : 0.f;
        }
      }
    }

    // ---- mask + online softmax (exp2 domain) ----
    float rmax[4] = {-3e38f, -3e38f, -3e38f, -3e38f};
#pragma unroll
    for (int ct = 0; ct < 4; ++ct)
#pragma unroll
      for (int r4 = 0; r4 < 4; ++r4) {
        float s = fmaf(mpf[ct][r4] - 1.f, MASKF, sc[ct][r4]);
        sc[ct][r4] = s;
        rmax[r4] = fmaxf(rmax[r4], s);
      }
#pragma unroll
    for (int r4 = 0; r4 < 4; ++r4)
#pragma unroll
      for (int off = 1; off < 16; off <<= 1)
        rmax[r4] = fmaxf(rmax[r4], __shfl_xor(rmax[r4], off));
    float scl[4], rsum[4];
#pragma unroll
    for (int r4 = 0; r4 < 4; ++r4) {
      float mnew = fmaxf(mrun[r4], rmax[r4]);
      scl[r4] = fexp2(mrun[r4] - mnew);
      mrun[r4] = mnew;
      rsum[r4] = 0.f;
    }
#pragma unroll
    for (int ct = 0; ct < 4; ++ct)
#pragma unroll
      for (int r4 = 0; r4 < 4; ++r4) {
        float p = fexp2(sc[ct][r4] - mrun[r4]);
        sc[ct][r4] = p;
        rsum[r4] += p;
      }
#pragma unroll
    for (int r4 = 0; r4 < 4; ++r4) {
#pragma unroll
      for (int off = 1; off < 16; off <<= 1)
        rsum[r4] += __shfl_xor(rsum[r4], off);
      lrun[r4] = lrun[r4] * scl[r4] + rsum[r4];
    }
#pragma unroll
    for (int ct = 0; ct < 4; ++ct)
#pragma unroll
      for (int r4 = 0; r4 < 4; ++r4) oacc[ct][r4] *= scl[r4];

    // ---- P -> LDS (wave-private buffer) ----
#pragma unroll
    for (int ct = 0; ct < 4; ++ct)
#pragma unroll
      for (int r4 = 0; r4 < 4; ++r4)
        p_w[(g * 4 + r4) * 72 + ct * 16 + li] = (bf16_t)sc[ct][r4];

    // ---- PV ----
#pragma unroll
    for (int kkh = 0; kkh < 2; ++kkh) {
      bf16x8 ap = *(const bf16x8*)&p_w[li * 72 + kkh * 32 + g * 8];
#pragma unroll
      for (int ct = 0; ct < 4; ++ct) {
        int d = ct * 16 + li;
        int u2 = (kkh * 4 + g) ^ (d >> 3);
        bf16x8 bv = *(const bf16x8*)&vt_s[d * 72 + u2 * 8];
        oacc[ct] = __builtin_amdgcn_mfma_f32_16x16x32_bf16(ap, bv, oacc[ct], 0, 0, 0);
      }
    }

    // ---- roll mask prefetch ----
#pragma unroll
    for (int ct = 0; ct < 4; ++ct)
#pragma unroll
      for (int r4 = 0; r4 < 4; ++r4) mpf[ct][r4] = mnext[ct][r4];
  }

  // ---- normalize + write ----
#pragma unroll
  for (int ct = 0; ct < 4; ++ct)
#pragma unroll
    for (int r4 = 0; r4 < 4; ++r4) {
      int row = t0 + w * 16 + g * 4 + r4;
      float o = oacc[ct][r4] / lrun[r4];
      attnb[base_bh + (size_t)row * 1024 + ct * 16 + li] = (bf16_t)o;
    }
}

// ---------------- launcher ----------------
extern "C" void kernel_launch(void* const* d_in, const int* in_sizes, int n_in,
                              void* d_out, int out_size, void* d_ws, size_t ws_size,
                              hipStream_t stream) {
  (void)in_sizes; (void)n_in; (void)out_size; (void)ws_size;
  const float* x    = (const float*)d_in[0];
  const float* y    = (const float*)d_in[1];
  const float* mask = (const float*)d_in[2];
  const float* Wq   = (const float*)d_in[3];
  const float* bq   = (const float*)d_in[4];
  const float* Wk   = (const float*)d_in[5];
  const float* bk   = (const float*)d_in[6];
  const float* Wv   = (const float*)d_in[7];
  const float* bv   = (const float*)d_in[8];
  const float* Wp   = (const float*)d_in[9];
  const float* bp   = (const float*)d_in[10];
  const float* rwb  = (const float*)d_in[11];
  const float* rrb  = (const float*)d_in[12];
  const float* Wo   = (const float*)d_in[13];
  const float* bo   = (const float*)d_in[14];
  float* out = (float*)d_out;

  char* ws = (char*)d_ws;
  bf16_t* xb   = (bf16_t*)(ws + 0);            // 8 MB (reused as attnb later)
  bf16_t* yb   = (bf16_t*)(ws + (8ll << 20));
  bf16_t* Wqt  = (bf16_t*)(ws + (16ll << 20));
  bf16_t* Wkt  = (bf16_t*)(ws + (18ll << 20));
  bf16_t* Wvt  = (bf16_t*)(ws + (20ll << 20));
  bf16_t* Wpt  = (bf16_t*)(ws + (22ll << 20));
  bf16_t* Wot  = (bf16_t*)(ws + (24ll << 20));
  bf16_t* sint = (bf16_t*)(ws + (26ll << 20)); // 4 MB
  bf16_t* qwb  = (bf16_t*)(ws + (30ll << 20)); // 8 MB (q + r_w_bias, pre-scaled)
  bf16_t* kbuf = (bf16_t*)(ws + (46ll << 20));
  bf16_t* vbuf = (bf16_t*)(ws + (54ll << 20));
  bf16_t* peb  = (bf16_t*)(ws + (62ll << 20)); // 4 MB
  bf16_t* attnb = xb;                          // alias: x consumed before attn writes

  k_cast_bf16<<<2048, 256, 0, stream>>>(x, xb, 1048576);
  k_cast_bf16<<<2048, 256, 0, stream>>>(y, yb, 1048576);
  dim3 tg(16, 16);
  k_transpose_cast<<<tg, 256, 0, stream>>>(Wq, Wqt);
  k_transpose_cast<<<tg, 256, 0, stream>>>(Wk, Wkt);
  k_transpose_cast<<<tg, 256, 0, stream>>>(Wv, Wvt);
  k_transpose_cast<<<tg, 256, 0, stream>>>(Wp, Wpt);
  k_transpose_cast<<<tg, 256, 0, stream>>>(Wo, Wot);
  k_sinusoid<<<2048, 512, 0, stream>>>(sint);

  dim3 g1(32, 8);  // M=4096
  dim3 g2(16, 8);  // M=2048
  k_gemm<<<g1, 256, 0, stream>>>(xb, Wqt, bq, rwb, QSCALE, qwb, nullptr);
  k_gemm<<<g1, 256, 0, stream>>>(yb, Wkt, bk, nullptr, 1.f, kbuf, nullptr);
  k_gemm<<<g1, 256, 0, stream>>>(yb, Wvt, bv, nullptr, 1.f, vbuf, nullptr);
  k_gemm<<<g2, 256, 0, stream>>>(sint, Wpt, bp, nullptr, 1.f, peb, nullptr);

  k_attn<<<1024, 256, 0, stream>>>(qwb, kbuf, vbuf, peb, rwb, rrb, mask, attnb);

  k_gemm<<<g1, 256, 0, stream>>>(attnb, Wot, bo, nullptr, 1.f, nullptr, out);
}